// Round 1
// baseline (661.643 us; speedup 1.0000x reference)
//
#include <hip/hip_runtime.h>
#include <hip/hip_bf16.h>
#include <stdint.h>
#include <stddef.h>

// DCNv2 forward: B=4, H=W=96, C=256, F=256, K=9 (3x3, same, stride1, dil1), DG=1.
// Pipeline: [k_om] fp32 partial conv (per-kh) -> ws
//           [k_wt] transpose main GEMM weight to [F][K*C] bf16 -> ws
//           [k_sample] sum partials + offsets/mask + bilinear sample -> cols bf16 [36864][2304] -> ws
//           [k_gemm] 128x128-tile bf16 MFMA GEMM (m97 structure) + bias -> out fp32

namespace {
constexpr int H  = 96, W = 96, C = 256, F = 256;
constexpr int NP = 4 * 96 * 96;   // 36864 output pixels
constexpr int KC = 9 * 256;       // 2304 = GEMM K
}

typedef __attribute__((ext_vector_type(8))) short bf16x8;   // 8 bf16 in 4 VGPRs (guide §3)
typedef __attribute__((ext_vector_type(4))) float floatx4;

__device__ __forceinline__ void load_lds16(const void* g, void* l) {
  __builtin_amdgcn_global_load_lds((const __attribute__((address_space(1))) void*)g,
                                   (__attribute__((address_space(3))) void*)l,
                                   16, 0, 0);
}

// ---------------- kernel 1: om partial conv (one kh slice per block.y) ----------------
// pOm layout: [kh][27][NP] fp32 so stores are coalesced across p.
__global__ __launch_bounds__(256) void k_om(const float* __restrict__ x,
                                            const float* __restrict__ omk,
                                            float* __restrict__ pOm) {
  const int p  = blockIdx.x * 256 + threadIdx.x;
  const int kh = blockIdx.y;
  const int b  = p / (H * W);
  const int hw = p % (H * W);
  const int h = hw / W, w = hw % W;

  float acc[27];
#pragma unroll
  for (int i = 0; i < 27; ++i) acc[i] = 0.f;

  const int y = h - 1 + kh;
  if (y >= 0 && y < H) {
#pragma unroll 1
    for (int kw = 0; kw < 3; ++kw) {
      const int xx = w - 1 + kw;
      if (xx < 0 || xx >= W) continue;
      const float* __restrict__ xb = x + (size_t)((b * H + y) * W + xx) * C;
      const float* __restrict__ wb = omk + (size_t)(kh * 3 + kw) * C * 27;
#pragma unroll 1
      for (int c = 0; c < C; ++c) {
        const float xv = xb[c];               // vector load, per-pixel
#pragma unroll
        for (int oc = 0; oc < 27; ++oc)       // weights thread-uniform -> scalar loads
          acc[oc] += xv * wb[c * 27 + oc];
      }
    }
  }
#pragma unroll
  for (int oc = 0; oc < 27; ++oc)
    pOm[(size_t)(kh * 27 + oc) * NP + p] = acc[oc];   // coalesced across p
}

// ---------------- kernel 2: transpose + bf16-convert main weight ----------------
// kern: [KC][F] fp32  ->  wt: [F][KC] bf16 (rows k-contiguous for MFMA B staging)
__global__ __launch_bounds__(256) void k_wt(const float* __restrict__ kern,
                                            __hip_bfloat16* __restrict__ wt) {
  const int kc = blockIdx.x;    // 0..2303
  const int f  = threadIdx.x;   // 0..255
  wt[(size_t)f * KC + kc] = __float2bfloat16(kern[(size_t)kc * F + f]);
}

// ---------------- kernel 3: offsets/mask + bilinear sampling -> cols bf16 ----------------
__global__ __launch_bounds__(256) void k_sample(const float* __restrict__ x,
                                                const float* __restrict__ pOm,
                                                const float* __restrict__ om_bias,
                                                __hip_bfloat16* __restrict__ cols) {
  const int p  = blockIdx.x;    // pixel
  const int c  = threadIdx.x;   // channel
  const int b  = p / (H * W);
  const int hw = p % (H * W);
  const int h = hw / W, w = hw % W;

  __shared__ float s_py[9], s_px[9], s_m[9];
  if (threadIdx.x < 9) {
    const int k = threadIdx.x;
    float dy = om_bias[2 * k], dx = om_bias[2 * k + 1], mv = om_bias[18 + k];
#pragma unroll
    for (int kh = 0; kh < 3; ++kh) {
      dy += pOm[(size_t)(kh * 27 + 2 * k)     * NP + p];
      dx += pOm[(size_t)(kh * 27 + 2 * k + 1) * NP + p];
      mv += pOm[(size_t)(kh * 27 + 18 + k)    * NP + p];
    }
    s_py[k] = (float)(h - 1 + k / 3) + dy;
    s_px[k] = (float)(w - 1 + k % 3) + dx;
    s_m[k]  = 2.f / (1.f + __expf(-mv));   // sigmoid(mv)*2
  }
  __syncthreads();

  const float* __restrict__ xb = x + (size_t)b * (H * W * C);
  __hip_bfloat16* __restrict__ ob = cols + (size_t)p * KC;

#pragma unroll 1
  for (int k = 0; k < 9; ++k) {
    const float py = s_py[k], px = s_px[k], m = s_m[k];
    const float y0f = floorf(py), x0f = floorf(px);
    const float fy = py - y0f, fx = px - x0f;
    const int y0 = (int)y0f, x0 = (int)x0f;
    float val = 0.f;
#pragma unroll
    for (int dy2 = 0; dy2 < 2; ++dy2) {
#pragma unroll
      for (int dx2 = 0; dx2 < 2; ++dx2) {
        const int yi = y0 + dy2, xi = x0 + dx2;
        if (yi >= 0 && yi < H && xi >= 0 && xi < W) {
          const float wgt = (dy2 ? fy : 1.f - fy) * (dx2 ? fx : 1.f - fx);
          val += wgt * xb[(size_t)(yi * W + xi) * C + c];   // coalesced over c
        }
      }
    }
    ob[k * C + c] = __float2bfloat16(val * m);   // coalesced 512B row
  }
}

// ---------------- kernel 4: bf16 MFMA GEMM, 128x128 tile, m97 structure ----------------
// A = cols [NP][KC] bf16 row-major; Bt = wt [F][KC] bf16 (i.e. B^T); out [NP][F] fp32 + bias.
__global__ __launch_bounds__(256) void k_gemm(const __hip_bfloat16* __restrict__ A,
                                              const __hip_bfloat16* __restrict__ Bt,
                                              const float* __restrict__ bias,
                                              float* __restrict__ out) {
  __shared__ __align__(16) char lds[16384];   // A tile [128][32] bf16 @0, B tile [128][32] bf16 @8192

  const int tid  = threadIdx.x;
  const int m0   = blockIdx.x * 128;
  const int n0   = blockIdx.y * 128;
  const int lane = tid & 63, wave = tid >> 6;
  const int wm = wave & 1, wn = wave >> 1;          // 2x2 waves of 64x64
  const int quad = lane >> 4, l16 = lane & 15;

  floatx4 acc[4][4];
#pragma unroll
  for (int i = 0; i < 4; ++i)
#pragma unroll
    for (int j = 0; j < 4; ++j) acc[i][j] = (floatx4){0.f, 0.f, 0.f, 0.f};

#pragma unroll 1
  for (int k0 = 0; k0 < KC; k0 += 32) {
    __syncthreads();   // previous iter's LDS reads done
#pragma unroll
    for (int j = 0; j < 2; ++j) {
      const int idx = tid + j * 256;          // 0..511 -> 16B chunk id
      const int row = idx >> 2, kp = idx & 3; // row in tile, 8-elem group in k
      load_lds16(A  + (size_t)(m0 + row) * KC + k0 + kp * 8, &lds[idx * 16]);
      load_lds16(Bt + (size_t)(n0 + row) * KC + k0 + kp * 8, &lds[8192 + idx * 16]);
    }
    __syncthreads();   // drains vmcnt -> staged data visible

    bf16x8 af[4], bfr[4];
#pragma unroll
    for (int mt = 0; mt < 4; ++mt)
      af[mt] = *(const bf16x8*)&lds[((wm * 64 + mt * 16 + l16) * 32 + quad * 8) * 2];
#pragma unroll
    for (int nt = 0; nt < 4; ++nt)
      bfr[nt] = *(const bf16x8*)&lds[8192 + ((wn * 64 + nt * 16 + l16) * 32 + quad * 8) * 2];
#pragma unroll
    for (int mt = 0; mt < 4; ++mt)
#pragma unroll
      for (int nt = 0; nt < 4; ++nt)
        acc[mt][nt] = __builtin_amdgcn_mfma_f32_16x16x32_bf16(af[mt], bfr[nt], acc[mt][nt], 0, 0, 0);
  }

  // epilogue: C/D layout col=lane&15, row=quad*4+reg (m89-verified), + bias
#pragma unroll
  for (int mt = 0; mt < 4; ++mt) {
#pragma unroll
    for (int nt = 0; nt < 4; ++nt) {
      const int gm = m0 + wm * 64 + mt * 16 + quad * 4;
      const int gn = n0 + wn * 64 + nt * 16 + l16;
      const float bs = bias[gn];
#pragma unroll
      for (int r = 0; r < 4; ++r)
        out[(size_t)(gm + r) * F + gn] = acc[mt][nt][r] + bs;
    }
  }
}

extern "C" void kernel_launch(void* const* d_in, const int* in_sizes, int n_in,
                              void* d_out, int out_size, void* d_ws, size_t ws_size,
                              hipStream_t stream) {
  const float* x    = (const float*)d_in[0];   // [4,96,96,256]
  const float* omk  = (const float*)d_in[1];   // [3,3,256,27]
  const float* omb  = (const float*)d_in[2];   // [27]
  const float* kern = (const float*)d_in[3];   // [2304,256]
  const float* bias = (const float*)d_in[4];   // [256]
  float* out = (float*)d_out;                  // [4,96,96,256]

  char* ws = (char*)d_ws;
  __hip_bfloat16* wt   = (__hip_bfloat16*)ws;                        // 256*2304*2  = 1,179,648 B
  float*          pOm  = (float*)(ws + 1179648);                     // 81*36864*4  = 11,943,936 B
  __hip_bfloat16* cols = (__hip_bfloat16*)(ws + 1179648 + 11943936); // 36864*2304*2 = 169,869,312 B

  k_om    <<<dim3(NP / 256, 3), 256, 0, stream>>>(x, omk, pOm);
  k_wt    <<<dim3(KC),          256, 0, stream>>>(kern, wt);
  k_sample<<<dim3(NP),          256, 0, stream>>>(x, pOm, omb, cols);
  k_gemm  <<<dim3(NP / 128, F / 128), 256, 0, stream>>>(cols, wt, bias, out);
}

// Round 2
// 297.602 us; speedup vs baseline: 2.2232x; 2.2232x over previous
//
#include <hip/hip_runtime.h>
#include <hip/hip_bf16.h>
#include <stdint.h>
#include <stddef.h>

// DCNv2 forward: B=4, H=W=96, C=256, F=256, K=9 (3x3, same, stride1, dil1), DG=1.
// R1: replace latency-bound k_om (340us, 9.8% VALU, 17.9% occ) with MFMA implicit-im2col
//     GEMM over zero-halo-padded bf16 x; k_sample gathers bf16 pairs from padded xp.
// Pipeline: [k_pad]    x fp32 -> xp bf16 [4][98][98][256] with zero halo
//           [k_omw]    om weights -> wom bf16 [32][2304] (oc-major, k-contig, rows 27..31 = 0)
//           [k_wt]     main weight -> wt bf16 [256][2304] (f-major, k-contig)
//           [k_omgemm] MFMA GEMM M=36864 N=32 K=2304, A = implicit im2col(xp) -> pOm fp32 [NP][32]
//           [k_sample] offsets/mask + bilinear sample (bf16x2 gathers) -> cols bf16 [NP][2304]
//           [k_gemm]   128x128 bf16 MFMA GEMM + bias -> out fp32

namespace {
constexpr int H  = 96, W = 96, C = 256, F = 256;
constexpr int HP = 98;            // padded spatial dim (1-px zero halo)
constexpr int NP = 4 * 96 * 96;   // 36864 output pixels
constexpr int KC = 9 * 256;       // 2304 = GEMM K
}

typedef __attribute__((ext_vector_type(8))) short bf16x8;
typedef __attribute__((ext_vector_type(4))) float floatx4;

__device__ __forceinline__ void load_lds16(const void* g, void* l) {
  __builtin_amdgcn_global_load_lds((const __attribute__((address_space(1))) void*)g,
                                   (__attribute__((address_space(3))) void*)l,
                                   16, 0, 0);
}

__device__ __forceinline__ unsigned short bf16bits(float f) {
  __hip_bfloat16 h = __float2bfloat16(f);
  return *reinterpret_cast<unsigned short*>(&h);
}

// ---------------- k_pad: x fp32 -> xp bf16 with zero halo ----------------
__global__ __launch_bounds__(256) void k_pad(const float* __restrict__ x,
                                             __hip_bfloat16* __restrict__ xp) {
  const int pp = blockIdx.x;            // 0 .. 4*98*98-1
  const int c  = threadIdx.x;
  const int b  = pp / (HP * HP);
  const int r  = pp % (HP * HP);
  const int y  = r / HP, xq = r % HP;
  float v = 0.f;
  if (y >= 1 && y <= H && xq >= 1 && xq <= W)
    v = x[((size_t)((b * H + (y - 1)) * W + (xq - 1))) * C + c];
  xp[(size_t)pp * C + c] = __float2bfloat16(v);
}

// ---------------- k_omw: omk [9*256][27] -> wom [32][2304] bf16, zero-pad rows ----------------
__global__ __launch_bounds__(256) void k_omw(const float* __restrict__ omk,
                                             __hip_bfloat16* __restrict__ wom) {
  const int kk = blockIdx.x;   // 0..8
  const int oc = blockIdx.y;   // 0..31
  const int c  = threadIdx.x;  // 0..255
  float v = (oc < 27) ? omk[(size_t)(kk * 256 + c) * 27 + oc] : 0.f;
  wom[(size_t)oc * KC + kk * 256 + c] = __float2bfloat16(v);
}

// ---------------- k_wt: kern [KC][F] fp32 -> wt [F][KC] bf16 ----------------
__global__ __launch_bounds__(256) void k_wt(const float* __restrict__ kern,
                                            __hip_bfloat16* __restrict__ wt) {
  const int kc = blockIdx.x;    // 0..2303
  const int f  = threadIdx.x;   // 0..255
  wt[(size_t)f * KC + kc] = __float2bfloat16(kern[(size_t)kc * F + f]);
}

// ---------------- k_omgemm: implicit-im2col MFMA GEMM, tile 128(M) x 32(N) ----------------
// A[p][kk*256+c] = xp[b][h+kh][w+kw][c]  (padded coords, always in-bounds)
// B = wom [32][2304]; out pOm [NP][32] fp32.
__global__ __launch_bounds__(256) void k_omgemm(const __hip_bfloat16* __restrict__ xp,
                                                const __hip_bfloat16* __restrict__ wom,
                                                float* __restrict__ pOm) {
  __shared__ __align__(16) char lds[10240];  // A [128][32]bf16 @0 (8KB), B [32][32]bf16 @8192 (2KB)
  const int tid  = threadIdx.x;
  const int m0   = blockIdx.x * 128;
  const int lane = tid & 63, wave = tid >> 6;
  const int quad = lane >> 4, l16 = lane & 15;

  // Each thread stages two A rows (tid>>2, 64+(tid>>2)), 16B chunk kp = tid&3.
  const int kp = tid & 3;
  const __hip_bfloat16* abase[2];
#pragma unroll
  for (int j = 0; j < 2; ++j) {
    const int row = (tid >> 2) + j * 64;
    const int p = m0 + row;
    const int b = p / (H * W);
    const int hw = p % (H * W);
    const int h = hw / W, w = hw % W;
    abase[j] = xp + ((size_t)(b * HP + h) * HP + w) * C + kp * 8;
  }
  const __hip_bfloat16* bbase = wom + (size_t)(tid >> 2) * KC + kp * 8;  // tid<128 only

  floatx4 acc[2][2];
#pragma unroll
  for (int i = 0; i < 2; ++i)
#pragma unroll
    for (int j = 0; j < 2; ++j) acc[i][j] = (floatx4){0.f, 0.f, 0.f, 0.f};

#pragma unroll 1
  for (int k0 = 0; k0 < KC; k0 += 32) {
    const int kk = k0 >> 8;                 // 32-chunks never straddle a kk boundary
    const int c0 = k0 & 255;
    const int kh = kk / 3, kw = kk % 3;
    const int aoff = (kh * HP + kw) * C + c0;  // wave-uniform

    __syncthreads();
    load_lds16(abase[0] + aoff, &lds[tid * 16]);
    load_lds16(abase[1] + aoff, &lds[4096 + tid * 16]);
    if (tid < 128) load_lds16(bbase + k0, &lds[8192 + tid * 16]);
    __syncthreads();

    bf16x8 af[2], bfr[2];
#pragma unroll
    for (int mt = 0; mt < 2; ++mt)
      af[mt] = *(const bf16x8*)&lds[((wave * 32 + mt * 16 + l16) * 32 + quad * 8) * 2];
#pragma unroll
    for (int nt = 0; nt < 2; ++nt)
      bfr[nt] = *(const bf16x8*)&lds[8192 + ((nt * 16 + l16) * 32 + quad * 8) * 2];
#pragma unroll
    for (int mt = 0; mt < 2; ++mt)
#pragma unroll
      for (int nt = 0; nt < 2; ++nt)
        acc[mt][nt] = __builtin_amdgcn_mfma_f32_16x16x32_bf16(af[mt], bfr[nt], acc[mt][nt], 0, 0, 0);
  }

#pragma unroll
  for (int mt = 0; mt < 2; ++mt)
#pragma unroll
    for (int nt = 0; nt < 2; ++nt) {
      const int gm = m0 + wave * 32 + mt * 16 + quad * 4;
      const int gn = nt * 16 + l16;
#pragma unroll
      for (int r = 0; r < 4; ++r)
        pOm[(size_t)(gm + r) * 32 + gn] = acc[mt][nt][r];
    }
}

// ---------------- k_sample: 2 pixels/block, 2 channels/thread (bf16x2) ----------------
__global__ __launch_bounds__(256) void k_sample(const __hip_bfloat16* __restrict__ xp,
                                                const float* __restrict__ pOm,
                                                const float* __restrict__ om_bias,
                                                __hip_bfloat16* __restrict__ cols) {
  const int tid = threadIdx.x;
  const int sub = tid >> 7, cid = tid & 127;       // pixel-in-block, channel-pair
  const int p   = blockIdx.x * 2 + sub;
  const int b   = p / (H * W);
  const int hw  = p % (H * W);
  const int h = hw / W, w = hw % W;

  __shared__ float s_py[2][9], s_px[2][9], s_m[2][9];
  if (cid < 9) {
    const int k = cid;
    const float dy = om_bias[2 * k]     + pOm[(size_t)p * 32 + 2 * k];
    const float dx = om_bias[2 * k + 1] + pOm[(size_t)p * 32 + 2 * k + 1];
    const float mv = om_bias[18 + k]    + pOm[(size_t)p * 32 + 18 + k];
    s_py[sub][k] = (float)(h - 1 + k / 3) + dy;
    s_px[sub][k] = (float)(w - 1 + k % 3) + dx;
    s_m[sub][k]  = 2.f / (1.f + __expf(-mv));
  }
  __syncthreads();

  const uint32_t* __restrict__ xb = (const uint32_t*)(xp + (size_t)b * (HP * HP * C)) + cid;
  uint32_t* __restrict__ ob = (uint32_t*)(cols + (size_t)p * KC) + cid;

#pragma unroll 1
  for (int k = 0; k < 9; ++k) {
    const float py = s_py[sub][k], px = s_px[sub][k], m = s_m[sub][k];
    const float y0f = floorf(py), x0f = floorf(px);
    const float fy = py - y0f, fx = px - x0f;
    const int y0 = (int)y0f, x0 = (int)x0f;
    float v0 = 0.f, v1 = 0.f;
#pragma unroll
    for (int dy2 = 0; dy2 < 2; ++dy2) {
#pragma unroll
      for (int dx2 = 0; dx2 < 2; ++dx2) {
        const int yi = y0 + dy2, xi = x0 + dx2;
        const bool valid = (yi >= 0) & (yi < H) & (xi >= 0) & (xi < W);
        const float wgt = valid ? (dy2 ? fy : 1.f - fy) * (dx2 ? fx : 1.f - fx) : 0.f;
        // padded coords (clamped so reads are always in-bounds; weight 0 when invalid)
        const int yc = min(max(yi + 1, 0), HP - 1);
        const int xc = min(max(xi + 1, 0), HP - 1);
        const uint32_t v = xb[(size_t)(yc * HP + xc) * 128];
        v0 += wgt * __uint_as_float(v << 16);
        v1 += wgt * __uint_as_float(v & 0xffff0000u);
      }
    }
    const uint32_t packed = (uint32_t)bf16bits(v0 * m) | ((uint32_t)bf16bits(v1 * m) << 16);
    ob[k * 128] = packed;
  }
}

// ---------------- k_gemm: bf16 MFMA GEMM, 128x128 tile (m97 structure) ----------------
__global__ __launch_bounds__(256) void k_gemm(const __hip_bfloat16* __restrict__ A,
                                              const __hip_bfloat16* __restrict__ Bt,
                                              const float* __restrict__ bias,
                                              float* __restrict__ out) {
  __shared__ __align__(16) char lds[16384];   // A [128][32] @0, B [128][32] @8192

  const int tid  = threadIdx.x;
  const int m0   = blockIdx.x * 128;
  const int n0   = blockIdx.y * 128;
  const int lane = tid & 63, wave = tid >> 6;
  const int wm = wave & 1, wn = wave >> 1;
  const int quad = lane >> 4, l16 = lane & 15;

  floatx4 acc[4][4];
#pragma unroll
  for (int i = 0; i < 4; ++i)
#pragma unroll
    for (int j = 0; j < 4; ++j) acc[i][j] = (floatx4){0.f, 0.f, 0.f, 0.f};

#pragma unroll 1
  for (int k0 = 0; k0 < KC; k0 += 32) {
    __syncthreads();
#pragma unroll
    for (int j = 0; j < 2; ++j) {
      const int idx = tid + j * 256;
      const int row = idx >> 2, kp = idx & 3;
      load_lds16(A  + (size_t)(m0 + row) * KC + k0 + kp * 8, &lds[idx * 16]);
      load_lds16(Bt + (size_t)(n0 + row) * KC + k0 + kp * 8, &lds[8192 + idx * 16]);
    }
    __syncthreads();

    bf16x8 af[4], bfr[4];
#pragma unroll
    for (int mt = 0; mt < 4; ++mt)
      af[mt] = *(const bf16x8*)&lds[((wm * 64 + mt * 16 + l16) * 32 + quad * 8) * 2];
#pragma unroll
    for (int nt = 0; nt < 4; ++nt)
      bfr[nt] = *(const bf16x8*)&lds[8192 + ((wn * 64 + nt * 16 + l16) * 32 + quad * 8) * 2];
#pragma unroll
    for (int mt = 0; mt < 4; ++mt)
#pragma unroll
      for (int nt = 0; nt < 4; ++nt)
        acc[mt][nt] = __builtin_amdgcn_mfma_f32_16x16x32_bf16(af[mt], bfr[nt], acc[mt][nt], 0, 0, 0);
  }

#pragma unroll
  for (int mt = 0; mt < 4; ++mt) {
#pragma unroll
    for (int nt = 0; nt < 4; ++nt) {
      const int gm = m0 + wm * 64 + mt * 16 + quad * 4;
      const int gn = n0 + wn * 64 + nt * 16 + l16;
      const float bs = bias[gn];
#pragma unroll
      for (int r = 0; r < 4; ++r)
        out[(size_t)(gm + r) * F + gn] = acc[mt][nt][r] + bs;
    }
  }
}

extern "C" void kernel_launch(void* const* d_in, const int* in_sizes, int n_in,
                              void* d_out, int out_size, void* d_ws, size_t ws_size,
                              hipStream_t stream) {
  const float* x    = (const float*)d_in[0];   // [4,96,96,256]
  const float* omk  = (const float*)d_in[1];   // [3,3,256,27]
  const float* omb  = (const float*)d_in[2];   // [27]
  const float* kern = (const float*)d_in[3];   // [2304,256]
  const float* bias = (const float*)d_in[4];   // [256]
  float* out = (float*)d_out;                  // [4,96,96,256]

  char* ws = (char*)d_ws;
  size_t off = 0;
  __hip_bfloat16* wt   = (__hip_bfloat16*)(ws + off); off += (size_t)F * KC * 2;           // 1,179,648
  __hip_bfloat16* xp   = (__hip_bfloat16*)(ws + off); off += (size_t)4 * HP * HP * C * 2;  // 19,668,992
  __hip_bfloat16* wom  = (__hip_bfloat16*)(ws + off); off += (size_t)32 * KC * 2;          // 147,456
  float*          pOm  = (float*)(ws + off);          off += (size_t)NP * 32 * 4;          // 4,718,592
  __hip_bfloat16* cols = (__hip_bfloat16*)(ws + off);                                      // 169,869,312

  k_pad   <<<dim3(4 * HP * HP), 256, 0, stream>>>(x, xp);
  k_omw   <<<dim3(9, 32),       256, 0, stream>>>(omk, wom);
  k_wt    <<<dim3(KC),          256, 0, stream>>>(kern, wt);
  k_omgemm<<<dim3(NP / 128),    256, 0, stream>>>(xp, wom, pOm);
  k_sample<<<dim3(NP / 2),      256, 0, stream>>>(xp, pOm, omb, cols);
  k_gemm  <<<dim3(NP / 128, F / 128), 256, 0, stream>>>(cols, wt, bias, out);
}